// Round 7
// baseline (367.265 us; speedup 1.0000x reference)
//
#include <hip/hip_runtime.h>
#include <hip/hip_bf16.h>
#include <math.h>

// Transformer block (pre-LN attn + MLP), B=4 T=1024 H=1024 K=16 HD=64.
// GEMMs: bf16 MFMA 16x16x32, global_load_lds width=16 staging, BK=64 with
// xor-swizzled LDS chunk placement. Epilogue LDS tile unioned with staging.
// Attention: fused flash-style, exp2-domain softmax (scale 0.125*log2e folded
// into Q at QKV epilogue); masked logits FILLED with 1e-9 (full-row softmax);
// fully-masked K-tiles contribute exp(1e-9-m)*suffixV analytically.
// k_attn R7: K/V share one LDS buffer sequentially (49.6KB -> 3 blocks/CU);
// V-DMA overlaps softmax VALU; v_exp_f32 via __builtin_amdgcn_exp2f.

typedef __attribute__((ext_vector_type(8))) short bf16x8;
typedef __attribute__((ext_vector_type(4))) float f32x4;

#define DEVINL __device__ __forceinline__

#define LOG2E_SCALE 0.18033688f      /* 0.125 * log2(e) */
#define MASK2 1.4426950408889634e-9f /* 1e-9 * log2(e) */

DEVINL void stage16(const __hip_bfloat16* g, short* l) {
  __builtin_amdgcn_global_load_lds(
      (const __attribute__((address_space(1))) unsigned int*)g,
      (__attribute__((address_space(3))) unsigned int*)l, 16, 0, 0);
}

DEVINL float bf2f(short u) {
  unsigned x = ((unsigned)(unsigned short)u) << 16;
  float f; __builtin_memcpy(&f, &x, 4); return f;
}

DEVINL short f2bf_s(float f) {
  __hip_bfloat16 h = __float2bfloat16(f);
  short s; __builtin_memcpy(&s, &h, 2); return s;
}

DEVINL float block_sum(float v, float* sb) {
  #pragma unroll
  for (int o = 32; o; o >>= 1) v += __shfl_down(v, o);
  const int lane = threadIdx.x & 63, w = threadIdx.x >> 6;
  if (lane == 0) sb[w] = v;
  __syncthreads();
  float r = sb[0] + sb[1] + sb[2] + sb[3];
  __syncthreads();
  return r;
}

// ---- GEMM core BK=64: C[M,N] += A[M,Kd] * Bt[N,Kd]^T, 256 threads ----
template<int BM, int BN, int WM, int WN>
DEVINL void gemm_core64(const __hip_bfloat16* __restrict__ A, int lda,
                        const __hip_bfloat16* __restrict__ Bt, int ldb,
                        int Kd, int row0, int col0,
                        f32x4 (&acc)[WM/16][WN/16],
                        short* lds_a, short* lds_b) {
  constexpr int MI = WM / 16, NI = WN / 16, WNC = BN / WN;
  constexpr int CA = BM * 8, CB = BN * 8;  // 16B chunks per tile
  const int tid = threadIdx.x;
  const int lane = tid & 63, wave = tid >> 6;
  const int wm = (wave / WNC) * WM, wn = (wave % WNC) * WN;
  const int lr = lane & 15, lq = lane >> 4;
  for (int k0 = 0; k0 < Kd; k0 += 64) {
    #pragma unroll
    for (int c = tid; c < CA; c += 256) {
      const int r = c >> 3, kc = ((c & 7) ^ (r & 7)) << 3;
      stage16(A + (size_t)(row0 + r) * lda + k0 + kc, lds_a + c * 8);
    }
    #pragma unroll
    for (int c = tid; c < CB; c += 256) {
      const int r = c >> 3, kc = ((c & 7) ^ (r & 7)) << 3;
      stage16(Bt + (size_t)(col0 + r) * ldb + k0 + kc, lds_b + c * 8);
    }
    __syncthreads();
    #pragma unroll
    for (int s = 0; s < 2; s++) {
      bf16x8 af[MI], bfr[NI];
      #pragma unroll
      for (int mi = 0; mi < MI; mi++) {
        const int m = wm + mi * 16 + lr;
        af[mi] = *(const bf16x8*)(lds_a + m * 64 + (((s * 4 + lq) ^ (m & 7)) << 3));
      }
      #pragma unroll
      for (int ni = 0; ni < NI; ni++) {
        const int n = wn + ni * 16 + lr;
        bfr[ni] = *(const bf16x8*)(lds_b + n * 64 + (((s * 4 + lq) ^ (n & 7)) << 3));
      }
      #pragma unroll
      for (int mi = 0; mi < MI; mi++)
        #pragma unroll
        for (int ni = 0; ni < NI; ni++)
          acc[mi][ni] = __builtin_amdgcn_mfma_f32_16x16x32_bf16(
              af[mi], bfr[ni], acc[mi][ni], 0, 0, 0);
    }
    __syncthreads();
  }
}

// ---- transpose + f32->bf16: src[R][C] -> dst[(c+off)][r], dst pitch P ----
__global__ __launch_bounds__(256) void k_tcvt(const float* __restrict__ src,
                                              __hip_bfloat16* __restrict__ dst,
                                              int R, int C, int dstOff, int dstPitch) {
  __shared__ float tile[32][33];
  const int c0 = blockIdx.x * 32, r0 = blockIdx.y * 32;
  const int tx = threadIdx.x, ty = threadIdx.y;  // (32,8)
  #pragma unroll
  for (int i = 0; i < 32; i += 8)
    tile[ty + i][tx] = src[(size_t)(r0 + ty + i) * C + c0 + tx];
  __syncthreads();
  #pragma unroll
  for (int i = 0; i < 32; i += 8)
    dst[(size_t)(c0 + ty + i + dstOff) * dstPitch + r0 + tx] =
        __float2bfloat16(tile[tx][ty + i]);
}

// fused Wq/Wk/Wv transpose (z picks source; all 1024x1024, dst pitch 1024)
__global__ __launch_bounds__(256) void k_tcvt3(const float* __restrict__ Wq,
                                               const float* __restrict__ Wk,
                                               const float* __restrict__ Wv,
                                               __hip_bfloat16* __restrict__ dst) {
  __shared__ float tile[32][33];
  const float* src = blockIdx.z == 0 ? Wq : (blockIdx.z == 1 ? Wk : Wv);
  const int dstOff = blockIdx.z << 10;
  const int c0 = blockIdx.x * 32, r0 = blockIdx.y * 32;
  const int tx = threadIdx.x, ty = threadIdx.y;
  #pragma unroll
  for (int i = 0; i < 32; i += 8)
    tile[ty + i][tx] = src[(size_t)(r0 + ty + i) * 1024 + c0 + tx];
  __syncthreads();
  #pragma unroll
  for (int i = 0; i < 32; i += 8)
    dst[(size_t)(c0 + ty + i + dstOff) * 1024 + r0 + tx] =
        __float2bfloat16(tile[tx][ty + i]);
}

__global__ __launch_bounds__(256) void k_pack_bias(const float* __restrict__ bq,
                                                   const float* __restrict__ bk,
                                                   const float* __restrict__ bv,
                                                   float* __restrict__ o) {
  const int i = blockIdx.x * 256 + threadIdx.x;
  if (i < 3072)
    o[i] = i < 1024 ? bq[i] : (i < 2048 ? bk[i - 1024] : bv[i - 2048]);
}

// ---- LayerNorm (+residual add; optionally init out = x2 + b2) ----
__global__ __launch_bounds__(256) void k_ln(const float* __restrict__ x,
                                            const float* __restrict__ y,
                                            const float* __restrict__ g,
                                            const float* __restrict__ bb,
                                            __hip_bfloat16* __restrict__ o,
                                            float* __restrict__ x2o,
                                            const float* __restrict__ badd,
                                            float* __restrict__ oinit) {
  __shared__ float sb[4];
  const int t = threadIdx.x;
  const size_t base = (size_t)blockIdx.x * 1024 + t * 4;
  const int c = t * 4;
  float4 xv = *(const float4*)(x + base);
  if (y) {
    float4 yv = *(const float4*)(y + base);
    xv.x += yv.x; xv.y += yv.y; xv.z += yv.z; xv.w += yv.w;
    *(float4*)(x2o + base) = xv;
    float4 ov;
    ov.x = xv.x + badd[c + 0]; ov.y = xv.y + badd[c + 1];
    ov.z = xv.z + badd[c + 2]; ov.w = xv.w + badd[c + 3];
    *(float4*)(oinit + base) = ov;
  }
  const float mu = block_sum(xv.x + xv.y + xv.z + xv.w, sb) * (1.f / 1024.f);
  const float dx = xv.x - mu, dy = xv.y - mu, dz = xv.z - mu, dw = xv.w - mu;
  const float var = block_sum(dx * dx + dy * dy + dz * dz + dw * dw, sb) * (1.f / 1024.f);
  const float rs = rsqrtf(var + 1e-5f);
  o[base + 0] = __float2bfloat16(dx * rs * g[c + 0] + bb[c + 0]);
  o[base + 1] = __float2bfloat16(dy * rs * g[c + 1] + bb[c + 1]);
  o[base + 2] = __float2bfloat16(dz * rs * g[c + 2] + bb[c + 2]);
  o[base + 3] = __float2bfloat16(dw * rs * g[c + 3] + bb[c + 3]);
}

// ---- QKV GEMM: h1[4096,1024] @ Wqkv_t[3072,1024]^T -> Q/K [hb][t][d], Vt [hb][d][t]
// Q is PRE-SCALED by 0.125*log2e so attention logits are base-2.
__global__ __launch_bounds__(256) void k_gemm_qkv(
    const __hip_bfloat16* __restrict__ h1, const __hip_bfloat16* __restrict__ Wt,
    const float* __restrict__ bqkv, __hip_bfloat16* __restrict__ Q,
    __hip_bfloat16* __restrict__ K, __hip_bfloat16* __restrict__ Vt) {
  __shared__ alignas(16) short smem[16896];   // la(8192) lb(8192) | lc(16896)
  short* la = smem;
  short* lb = smem + 8192;
  short* lc = smem;
  const int row0 = blockIdx.x * 128, col0 = blockIdx.y * 128;
  f32x4 acc[4][4] = {};
  gemm_core64<128, 128, 64, 64>(h1, 1024, Wt, 1024, 1024, row0, col0, acc, la, lb);
  const int tid = threadIdx.x, lane = tid & 63, wave = tid >> 6;
  const int wm = (wave >> 1) * 64, wn = (wave & 1) * 64, lr = lane & 15, lq = lane >> 4;
  const int which = col0 >> 10;                 // uniform: 0=Q 1=K 2=V
  const int h0 = (col0 & 1023) >> 6;
  const int b = row0 >> 10, t0 = row0 & 1023;
  if (which < 2) {
    const float qs = (which == 0) ? LOG2E_SCALE : 1.f;
    #pragma unroll
    for (int mi = 0; mi < 4; mi++)
      #pragma unroll
      for (int ni = 0; ni < 4; ni++)
        #pragma unroll
        for (int r = 0; r < 4; r++) {
          const int row = wm + mi * 16 + lq * 4 + r;
          const int col = wn + ni * 16 + lr;
          lc[row * 132 + col] = f2bf_s((acc[mi][ni][r] + bqkv[col0 + col]) * qs);
        }
    __syncthreads();
    __hip_bfloat16* O = which == 0 ? Q : K;
    #pragma unroll
    for (int c = 0; c < 8; c++) {
      const int f = tid + 256 * c;              // flat 16B-chunk id
      const int r = f >> 4, cc = f & 15;
      const int col = cc * 8;
      const int head = h0 + (col >> 6), d = col & 63;
      float4 vv = *(const float4*)(lc + r * 132 + col);
      *(float4*)(O + (((size_t)(b * 16 + head)) << 16) + (t0 + r) * 64 + d) = vv;
    }
  } else {
    // transposed epilogue: lc[col][row]
    #pragma unroll
    for (int mi = 0; mi < 4; mi++)
      #pragma unroll
      for (int ni = 0; ni < 4; ni++)
        #pragma unroll
        for (int r = 0; r < 4; r++) {
          const int row = wm + mi * 16 + lq * 4 + r;
          const int col = wn + ni * 16 + lr;
          lc[col * 132 + row] = f2bf_s(acc[mi][ni][r] + bqkv[col0 + col]);
        }
    __syncthreads();
    #pragma unroll
    for (int c = 0; c < 8; c++) {
      const int f = tid + 256 * c;
      const int dl = f >> 4, tc = f & 15;       // local d 0..127, t-chunk
      const int head = h0 + (dl >> 6), d = dl & 63;
      float4 vv = *(const float4*)(lc + dl * 132 + tc * 8);
      *(float4*)(Vt + (((size_t)(b * 16 + head)) << 16) + (size_t)d * 1024 +
                 t0 + tc * 8) = vv;
    }
  }
}

// ---- tail V sums: TV[hb][qt][d] = sum_{t >= (qt+1)*128} Vt[hb][d][t] ----
__global__ __launch_bounds__(256) void k_tailv(const __hip_bfloat16* __restrict__ Vt,
                                               float* __restrict__ TV) {
  __shared__ float ts[8][64];
  const int hb = blockIdx.x, tid = threadIdx.x;
  const __hip_bfloat16* Vh = Vt + ((size_t)hb << 16);
  for (int w = tid; w < 512; w += 256) {
    const int kt = w >> 6, d = w & 63;
    const short* p = (const short*)(Vh + (size_t)d * 1024 + kt * 128);
    float s = 0.f;
    for (int j = 0; j < 128; j += 8) {
      bf16x8 v = *(const bf16x8*)(p + j);
      #pragma unroll
      for (int e = 0; e < 8; e++) s += bf2f(v[e]);
    }
    ts[kt][d] = s;
  }
  __syncthreads();
  for (int w = tid; w < 512; w += 256) {
    const int qt = w >> 6, d = w & 63;
    float s = 0.f;
    for (int kt = qt + 1; kt < 8; kt++) s += ts[kt][d];
    TV[((size_t)hb * 8 + qt) * 64 + d] = s;
  }
}

// ---- fused attention: one block = (128 q-rows, one head) ----
// LDS: lp (Q stage, then P-tile) + ONE shared K/V buffer (K dead after QK^T
// frag reads; V DMA overlaps softmax VALU). 49.6KB -> 3 blocks/CU.
__global__ __launch_bounds__(256, 3) void k_attn(
    const __hip_bfloat16* __restrict__ Q, const __hip_bfloat16* __restrict__ K,
    const __hip_bfloat16* __restrict__ Vt, const float* __restrict__ TV,
    float* __restrict__ y) {
  __shared__ short lp[128 * 130];  // Q staging, then P-tile (padded)
  __shared__ short lkv[128 * 64];  // K-tile then V^T-tile, swizzled
  const int hb = blockIdx.y;
  const int qt = (blockIdx.y & 32) ? (7 - (int)blockIdx.x) : (int)blockIdx.x;
  const int q0 = qt * 128;
  const int tid = threadIdx.x, lane = tid & 63, wave = tid >> 6;
  const int lr = lane & 15, lq = lane >> 4;
  const int wm = wave * 32;
  const __hip_bfloat16* Qh = Q + ((size_t)hb << 16);
  const __hip_bfloat16* Kh = K + ((size_t)hb << 16);
  const __hip_bfloat16* Vh = Vt + ((size_t)hb << 16);

  for (int c = tid; c < 1024; c += 256)
    stage16(Qh + (size_t)(q0 + (c >> 3)) * 64 + (((c & 7) ^ ((c >> 3) & 7)) << 3),
            lp + c * 8);
  __syncthreads();
  bf16x8 qf[2][2];
  #pragma unroll
  for (int mi = 0; mi < 2; mi++)
    #pragma unroll
    for (int s = 0; s < 2; s++) {
      const int m = wm + mi * 16 + lr;
      qf[mi][s] = *(const bf16x8*)(lp + m * 64 + (((s * 4 + lq) ^ (m & 7)) << 3));
    }

  f32x4 oacc[2][4] = {};
  float mrow[2][4], lrow[2][4];
  #pragma unroll
  for (int mi = 0; mi < 2; mi++)
    #pragma unroll
    for (int r = 0; r < 4; r++) { mrow[mi][r] = -1e30f; lrow[mi][r] = 0.f; }

  for (int kt = 0; kt <= qt; kt++) {
    const int k0 = kt * 128;
    __syncthreads();  // prev PV frag reads (lp, lkv) done
    for (int c = tid; c < 1024; c += 256)
      stage16(Kh + (size_t)(k0 + (c >> 3)) * 64 + (((c & 7) ^ ((c >> 3) & 7)) << 3),
              lkv + c * 8);
    __syncthreads();  // K visible
    f32x4 sacc[2][8] = {};
    #pragma unroll
    for (int s = 0; s < 2; s++) {
      bf16x8 bf[8];
      #pragma unroll
      for (int ni = 0; ni < 8; ni++) {
        const int n = ni * 16 + lr;
        bf[ni] = *(const bf16x8*)(lkv + n * 64 + (((s * 4 + lq) ^ (n & 7)) << 3));
      }
      #pragma unroll
      for (int mi = 0; mi < 2; mi++)
        #pragma unroll
        for (int ni = 0; ni < 8; ni++)
          sacc[mi][ni] = __builtin_amdgcn_mfma_f32_16x16x32_bf16(
              qf[mi][s], bf[ni], sacc[mi][ni], 0, 0, 0);
    }
    __syncthreads();  // K frag reads done; lkv free for V
    // V^T tile DMA (overlaps softmax VALU below)
    for (int c = tid; c < 1024; c += 256)
      stage16(Vh + (size_t)(c >> 4) * 1024 + k0 + (((c & 15) ^ ((c >> 4) & 15)) << 3),
              lkv + c * 8);
    // online softmax, base-2 domain (logits already scaled by 0.125*log2e)
    const bool diag = (kt == qt);
    #pragma unroll
    for (int mi = 0; mi < 2; mi++)
      #pragma unroll
      for (int r = 0; r < 4; r++) {
        const int il = wm + mi * 16 + lq * 4 + r;
        float tmax = -1e30f;
        #pragma unroll
        for (int ni = 0; ni < 8; ni++) {
          float v = sacc[mi][ni][r];
          if (diag && (ni * 16 + lr) > il) v = MASK2;
          sacc[mi][ni][r] = v;
          tmax = fmaxf(tmax, v);
        }
        #pragma unroll
        for (int msk = 8; msk; msk >>= 1) tmax = fmaxf(tmax, __shfl_xor(tmax, msk));
        const float mn = fmaxf(mrow[mi][r], tmax);
        const float al = __builtin_amdgcn_exp2f(mrow[mi][r] - mn);
        float rs = 0.f;
        #pragma unroll
        for (int ni = 0; ni < 8; ni++) {
          const float pv = __builtin_amdgcn_exp2f(sacc[mi][ni][r] - mn);
          sacc[mi][ni][r] = pv;
          rs += pv;
        }
        #pragma unroll
        for (int msk = 8; msk; msk >>= 1) rs += __shfl_xor(rs, msk);
        mrow[mi][r] = mn;
        lrow[mi][r] = lrow[mi][r] * al + rs;
        #pragma unroll
        for (int ni = 0; ni < 4; ni++) oacc[mi][ni][r] *= al;
      }
    // P -> lp (padded pitch 130)
    #pragma unroll
    for (int mi = 0; mi < 2; mi++)
      #pragma unroll
      for (int r = 0; r < 4; r++) {
        const int row = wm + mi * 16 + lq * 4 + r;
        #pragma unroll
        for (int ni = 0; ni < 8; ni++)
          ((short*)lp)[row * 130 + ni * 16 + lr] = f2bf_s(sacc[mi][ni][r]);
      }
    __syncthreads();  // V staged + P written
    #pragma unroll
    for (int ks = 0; ks < 4; ks++) {
      bf16x8 pa[2], vb[4];
      #pragma unroll
      for (int mi = 0; mi < 2; mi++)
        pa[mi] = *(const bf16x8*)(lp + (wm + mi * 16 + lr) * 130 + ks * 32 + lq * 8);
      #pragma unroll
      for (int ni = 0; ni < 4; ni++) {
        const int d = ni * 16 + lr;
        vb[ni] = *(const bf16x8*)(lkv + d * 128 + (((ks * 4 + lq) ^ (d & 15)) << 3));
      }
      #pragma unroll
      for (int mi = 0; mi < 2; mi++)
        #pragma unroll
        for (int ni = 0; ni < 4; ni++)
          oacc[mi][ni] = __builtin_amdgcn_mfma_f32_16x16x32_bf16(
              pa[mi], vb[ni], oacc[mi][ni], 0, 0, 0);
    }
  }

  const int b = hb >> 4, h = hb & 15;
  const float cv = (float)(1024 - (qt + 1) * 128);
  const float* tv = TV + ((size_t)hb * 8 + qt) * 64;
  #pragma unroll
  for (int mi = 0; mi < 2; mi++)
    #pragma unroll
    for (int r = 0; r < 4; r++) {
      const int t = q0 + wm + mi * 16 + lq * 4 + r;
      const float tail = __builtin_amdgcn_exp2f(MASK2 - mrow[mi][r]);
      const float inv = 1.f / (lrow[mi][r] + cv * tail);
      #pragma unroll
      for (int ni = 0; ni < 4; ni++) {
        const int d = ni * 16 + lr;
        y[((size_t)(b * 1024 + t) << 10) + h * 64 + d] =
            (oacc[mi][ni][r] + tail * tv[d]) * inv;
      }
    }
}

// ---- MLP1: h2 @ W1t^T + b1 -> exact gelu -> G bf16 [4096,4096] ----
__global__ __launch_bounds__(256) void k_gemm_mlp1(const __hip_bfloat16* __restrict__ h2,
                                                   const __hip_bfloat16* __restrict__ W1t,
                                                   const float* __restrict__ b1,
                                                   __hip_bfloat16* __restrict__ G) {
  __shared__ alignas(16) short smem[16896];
  short* la = smem;
  short* lb = smem + 8192;
  short* lc = smem;
  const int row0 = blockIdx.x * 128, col0 = blockIdx.y * 128;
  f32x4 acc[4][4] = {};
  gemm_core64<128, 128, 64, 64>(h2, 1024, W1t, 1024, 1024, row0, col0, acc, la, lb);
  const int tid = threadIdx.x, lane = tid & 63, wave = tid >> 6;
  const int wm = (wave >> 1) * 64, wn = (wave & 1) * 64, lr = lane & 15, lq = lane >> 4;
  #pragma unroll
  for (int mi = 0; mi < 4; mi++)
    #pragma unroll
    for (int ni = 0; ni < 4; ni++)
      #pragma unroll
      for (int r = 0; r < 4; r++) {
        const int row = wm + mi * 16 + lq * 4 + r;
        const int col = wn + ni * 16 + lr;
        float v = acc[mi][ni][r] + b1[col0 + col];
        v = 0.5f * v * (1.f + erff(v * 0.70710678118654752f));
        lc[row * 132 + col] = f2bf_s(v);
      }
  __syncthreads();
  #pragma unroll
  for (int c = 0; c < 8; c++) {
    const int f = tid + 256 * c;
    const int r = f >> 4, cc = f & 15;
    float4 vv = *(const float4*)(lc + r * 132 + cc * 8);
    *(float4*)(G + ((size_t)(row0 + r) << 12) + col0 + cc * 8) = vv;
  }
}

// ---- MLP2 split-K=2: out += G @ W2t^T (out pre-initialized with b2 + x2) ----
__global__ __launch_bounds__(256) void k_gemm_mlp2(const __hip_bfloat16* __restrict__ G,
                                                   const __hip_bfloat16* __restrict__ W2t,
                                                   float* __restrict__ out) {
  __shared__ alignas(16) short smem[16384];
  short* la = smem;
  short* lb = smem + 8192;
  const int row0 = blockIdx.x * 128, col0 = blockIdx.y * 128;
  const int kOff = blockIdx.z * 2048;
  f32x4 acc[4][4] = {};
  gemm_core64<128, 128, 64, 64>(G + kOff, 4096, W2t + kOff, 4096, 2048,
                                row0, col0, acc, la, lb);
  const int lane = threadIdx.x & 63, wave = threadIdx.x >> 6;
  const int wm = (wave >> 1) * 64, wn = (wave & 1) * 64, lr = lane & 15, lq = lane >> 4;
  #pragma unroll
  for (int mi = 0; mi < 4; mi++)
    #pragma unroll
    for (int ni = 0; ni < 4; ni++)
      #pragma unroll
      for (int r = 0; r < 4; r++) {
        const int grow = row0 + wm + mi * 16 + lq * 4 + r;
        const int gcol = col0 + wn + ni * 16 + lr;
        atomicAdd(out + (((size_t)grow << 10) + gcol), acc[mi][ni][r]);
      }
}

extern "C" void kernel_launch(void* const* d_in, const int* in_sizes, int n_in,
                              void* d_out, int out_size, void* d_ws, size_t ws_size,
                              hipStream_t stream) {
  const float* x     = (const float*)d_in[0];
  const float* ln1_g = (const float*)d_in[1];
  const float* ln1_b = (const float*)d_in[2];
  const float* ln2_g = (const float*)d_in[3];
  const float* ln2_b = (const float*)d_in[4];
  const float* Wq    = (const float*)d_in[5];
  const float* bq    = (const float*)d_in[6];
  const float* Wk    = (const float*)d_in[7];
  const float* bk    = (const float*)d_in[8];
  const float* Wv    = (const float*)d_in[9];
  const float* bv    = (const float*)d_in[10];
  const float* W1    = (const float*)d_in[11];
  const float* b1    = (const float*)d_in[12];
  const float* W2    = (const float*)d_in[13];
  const float* b2    = (const float*)d_in[14];
  float* out = (float*)d_out;

  char* p = (char*)d_ws;
  auto alloc = [&](size_t bytes) { char* r = p; p += (bytes + 255) & ~(size_t)255; return r; };
  __hip_bfloat16* wqkv = (__hip_bfloat16*)alloc(3072 * 1024 * 2);
  __hip_bfloat16* w1t  = (__hip_bfloat16*)alloc(4096 * 1024 * 2);
  __hip_bfloat16* w2t  = (__hip_bfloat16*)alloc(1024 * 4096 * 2);
  float*          bqkv = (float*)alloc(3072 * 4);
  __hip_bfloat16* h1   = (__hip_bfloat16*)alloc(4096 * 1024 * 2);
  __hip_bfloat16* Qb   = (__hip_bfloat16*)alloc((size_t)64 * 65536 * 2);  // [64][1024][64]
  __hip_bfloat16* Kb   = (__hip_bfloat16*)alloc((size_t)64 * 65536 * 2);
  __hip_bfloat16* Vt   = (__hip_bfloat16*)alloc((size_t)64 * 65536 * 2);  // [64][64][1024]
  float*          TV   = (float*)alloc((size_t)64 * 8 * 64 * 4);
  float*          yb   = (float*)alloc((size_t)4096 * 1024 * 4);
  float*          x2   = (float*)alloc((size_t)4096 * 1024 * 4);
  __hip_bfloat16* h2   = (__hip_bfloat16*)alloc(4096 * 1024 * 2);
  __hip_bfloat16* G    = (__hip_bfloat16*)alloc((size_t)4096 * 4096 * 2);
  (void)ws_size; (void)in_sizes; (void)n_in; (void)out_size;

  const dim3 b256(256), bt(32, 8);
  k_tcvt3<<<dim3(32, 32, 3), bt, 0, stream>>>(Wq, Wk, Wv, wqkv);
  k_tcvt<<<dim3(128, 32), bt, 0, stream>>>(W1, w1t, 1024, 4096, 0, 1024);
  k_tcvt<<<dim3(32, 128), bt, 0, stream>>>(W2, w2t, 4096, 1024, 0, 4096);
  k_pack_bias<<<12, b256, 0, stream>>>(bq, bk, bv, bqkv);

  k_ln<<<4096, b256, 0, stream>>>(x, nullptr, ln1_g, ln1_b, h1, nullptr, nullptr, nullptr);
  k_gemm_qkv<<<dim3(32, 24), b256, 0, stream>>>(h1, wqkv, bqkv, Qb, Kb, Vt);
  k_tailv<<<64, b256, 0, stream>>>(Vt, TV);
  k_attn<<<dim3(8, 64), b256, 0, stream>>>(Qb, Kb, Vt, TV, yb);

  k_ln<<<4096, b256, 0, stream>>>(x, yb, ln2_g, ln2_b, h2, x2, b2, out);
  k_gemm_mlp1<<<dim3(32, 32), b256, 0, stream>>>(h2, w1t, b1, G);
  k_gemm_mlp2<<<dim3(32, 8, 2), b256, 0, stream>>>(G, w2t, out);
}

// Round 8
// 339.275 us; speedup vs baseline: 1.0825x; 1.0825x over previous
//
#include <hip/hip_runtime.h>
#include <hip/hip_bf16.h>
#include <math.h>

// Transformer block (pre-LN attn + MLP), B=4 T=1024 H=1024 K=16 HD=64.
// GEMMs: bf16 MFMA 16x16x32, global_load_lds width=16 staging, BK=64 with
// xor-swizzled LDS chunk placement. Epilogue LDS tile unioned with staging.
// Attention R8: 64-row Q-tiles -> 1024 blocks (~4/CU, was 512/2 -> latency
// bound at Occ 13%); Q-frags via direct global loads (no staging barrier);
// K/V share one LDS buffer; exp2-domain softmax (0.125*log2e folded into Q);
// masked logits FILLED with 1e-9 (full-row softmax); fully-masked K-tiles
// contribute exp(1e-9-m)*suffixV analytically (TV precomputed).

typedef __attribute__((ext_vector_type(8))) short bf16x8;
typedef __attribute__((ext_vector_type(4))) float f32x4;

#define DEVINL __device__ __forceinline__

#define LOG2E_SCALE 0.18033688f      /* 0.125 * log2(e) */
#define MASK2 1.4426950408889634e-9f /* 1e-9 * log2(e) */

DEVINL void stage16(const __hip_bfloat16* g, short* l) {
  __builtin_amdgcn_global_load_lds(
      (const __attribute__((address_space(1))) unsigned int*)g,
      (__attribute__((address_space(3))) unsigned int*)l, 16, 0, 0);
}

DEVINL float bf2f(short u) {
  unsigned x = ((unsigned)(unsigned short)u) << 16;
  float f; __builtin_memcpy(&f, &x, 4); return f;
}

DEVINL short f2bf_s(float f) {
  __hip_bfloat16 h = __float2bfloat16(f);
  short s; __builtin_memcpy(&s, &h, 2); return s;
}

DEVINL float block_sum(float v, float* sb) {
  #pragma unroll
  for (int o = 32; o; o >>= 1) v += __shfl_down(v, o);
  const int lane = threadIdx.x & 63, w = threadIdx.x >> 6;
  if (lane == 0) sb[w] = v;
  __syncthreads();
  float r = sb[0] + sb[1] + sb[2] + sb[3];
  __syncthreads();
  return r;
}

// ---- GEMM core BK=64: C[M,N] += A[M,Kd] * Bt[N,Kd]^T, 256 threads ----
template<int BM, int BN, int WM, int WN>
DEVINL void gemm_core64(const __hip_bfloat16* __restrict__ A, int lda,
                        const __hip_bfloat16* __restrict__ Bt, int ldb,
                        int Kd, int row0, int col0,
                        f32x4 (&acc)[WM/16][WN/16],
                        short* lds_a, short* lds_b) {
  constexpr int MI = WM / 16, NI = WN / 16, WNC = BN / WN;
  constexpr int CA = BM * 8, CB = BN * 8;  // 16B chunks per tile
  const int tid = threadIdx.x;
  const int lane = tid & 63, wave = tid >> 6;
  const int wm = (wave / WNC) * WM, wn = (wave % WNC) * WN;
  const int lr = lane & 15, lq = lane >> 4;
  for (int k0 = 0; k0 < Kd; k0 += 64) {
    #pragma unroll
    for (int c = tid; c < CA; c += 256) {
      const int r = c >> 3, kc = ((c & 7) ^ (r & 7)) << 3;
      stage16(A + (size_t)(row0 + r) * lda + k0 + kc, lds_a + c * 8);
    }
    #pragma unroll
    for (int c = tid; c < CB; c += 256) {
      const int r = c >> 3, kc = ((c & 7) ^ (r & 7)) << 3;
      stage16(Bt + (size_t)(col0 + r) * ldb + k0 + kc, lds_b + c * 8);
    }
    __syncthreads();
    #pragma unroll
    for (int s = 0; s < 2; s++) {
      bf16x8 af[MI], bfr[NI];
      #pragma unroll
      for (int mi = 0; mi < MI; mi++) {
        const int m = wm + mi * 16 + lr;
        af[mi] = *(const bf16x8*)(lds_a + m * 64 + (((s * 4 + lq) ^ (m & 7)) << 3));
      }
      #pragma unroll
      for (int ni = 0; ni < NI; ni++) {
        const int n = wn + ni * 16 + lr;
        bfr[ni] = *(const bf16x8*)(lds_b + n * 64 + (((s * 4 + lq) ^ (n & 7)) << 3));
      }
      #pragma unroll
      for (int mi = 0; mi < MI; mi++)
        #pragma unroll
        for (int ni = 0; ni < NI; ni++)
          acc[mi][ni] = __builtin_amdgcn_mfma_f32_16x16x32_bf16(
              af[mi], bfr[ni], acc[mi][ni], 0, 0, 0);
    }
    __syncthreads();
  }
}

// ---- transpose + f32->bf16: src[R][C] -> dst[(c+off)][r], dst pitch P ----
__global__ __launch_bounds__(256) void k_tcvt(const float* __restrict__ src,
                                              __hip_bfloat16* __restrict__ dst,
                                              int R, int C, int dstOff, int dstPitch) {
  __shared__ float tile[32][33];
  const int c0 = blockIdx.x * 32, r0 = blockIdx.y * 32;
  const int tx = threadIdx.x, ty = threadIdx.y;  // (32,8)
  #pragma unroll
  for (int i = 0; i < 32; i += 8)
    tile[ty + i][tx] = src[(size_t)(r0 + ty + i) * C + c0 + tx];
  __syncthreads();
  #pragma unroll
  for (int i = 0; i < 32; i += 8)
    dst[(size_t)(c0 + ty + i + dstOff) * dstPitch + r0 + tx] =
        __float2bfloat16(tile[tx][ty + i]);
}

// fused Wq/Wk/Wv transpose (z picks source; all 1024x1024, dst pitch 1024)
__global__ __launch_bounds__(256) void k_tcvt3(const float* __restrict__ Wq,
                                               const float* __restrict__ Wk,
                                               const float* __restrict__ Wv,
                                               __hip_bfloat16* __restrict__ dst) {
  __shared__ float tile[32][33];
  const float* src = blockIdx.z == 0 ? Wq : (blockIdx.z == 1 ? Wk : Wv);
  const int dstOff = blockIdx.z << 10;
  const int c0 = blockIdx.x * 32, r0 = blockIdx.y * 32;
  const int tx = threadIdx.x, ty = threadIdx.y;
  #pragma unroll
  for (int i = 0; i < 32; i += 8)
    tile[ty + i][tx] = src[(size_t)(r0 + ty + i) * 1024 + c0 + tx];
  __syncthreads();
  #pragma unroll
  for (int i = 0; i < 32; i += 8)
    dst[(size_t)(c0 + ty + i + dstOff) * 1024 + r0 + tx] =
        __float2bfloat16(tile[tx][ty + i]);
}

__global__ __launch_bounds__(256) void k_pack_bias(const float* __restrict__ bq,
                                                   const float* __restrict__ bk,
                                                   const float* __restrict__ bv,
                                                   float* __restrict__ o) {
  const int i = blockIdx.x * 256 + threadIdx.x;
  if (i < 3072)
    o[i] = i < 1024 ? bq[i] : (i < 2048 ? bk[i - 1024] : bv[i - 2048]);
}

// ---- LayerNorm (+residual add; optionally init out = x2 + b2) ----
__global__ __launch_bounds__(256) void k_ln(const float* __restrict__ x,
                                            const float* __restrict__ y,
                                            const float* __restrict__ g,
                                            const float* __restrict__ bb,
                                            __hip_bfloat16* __restrict__ o,
                                            float* __restrict__ x2o,
                                            const float* __restrict__ badd,
                                            float* __restrict__ oinit) {
  __shared__ float sb[4];
  const int t = threadIdx.x;
  const size_t base = (size_t)blockIdx.x * 1024 + t * 4;
  const int c = t * 4;
  float4 xv = *(const float4*)(x + base);
  if (y) {
    float4 yv = *(const float4*)(y + base);
    xv.x += yv.x; xv.y += yv.y; xv.z += yv.z; xv.w += yv.w;
    *(float4*)(x2o + base) = xv;
    float4 ov;
    ov.x = xv.x + badd[c + 0]; ov.y = xv.y + badd[c + 1];
    ov.z = xv.z + badd[c + 2]; ov.w = xv.w + badd[c + 3];
    *(float4*)(oinit + base) = ov;
  }
  const float mu = block_sum(xv.x + xv.y + xv.z + xv.w, sb) * (1.f / 1024.f);
  const float dx = xv.x - mu, dy = xv.y - mu, dz = xv.z - mu, dw = xv.w - mu;
  const float var = block_sum(dx * dx + dy * dy + dz * dz + dw * dw, sb) * (1.f / 1024.f);
  const float rs = rsqrtf(var + 1e-5f);
  o[base + 0] = __float2bfloat16(dx * rs * g[c + 0] + bb[c + 0]);
  o[base + 1] = __float2bfloat16(dy * rs * g[c + 1] + bb[c + 1]);
  o[base + 2] = __float2bfloat16(dz * rs * g[c + 2] + bb[c + 2]);
  o[base + 3] = __float2bfloat16(dw * rs * g[c + 3] + bb[c + 3]);
}

// ---- QKV GEMM: h1[4096,1024] @ Wqkv_t[3072,1024]^T -> Q/K [hb][t][d], Vt [hb][d][t]
// Q is PRE-SCALED by 0.125*log2e so attention logits are base-2.
__global__ __launch_bounds__(256) void k_gemm_qkv(
    const __hip_bfloat16* __restrict__ h1, const __hip_bfloat16* __restrict__ Wt,
    const float* __restrict__ bqkv, __hip_bfloat16* __restrict__ Q,
    __hip_bfloat16* __restrict__ K, __hip_bfloat16* __restrict__ Vt) {
  __shared__ alignas(16) short smem[16896];   // la(8192) lb(8192) | lc(16896)
  short* la = smem;
  short* lb = smem + 8192;
  short* lc = smem;
  const int row0 = blockIdx.x * 128, col0 = blockIdx.y * 128;
  f32x4 acc[4][4] = {};
  gemm_core64<128, 128, 64, 64>(h1, 1024, Wt, 1024, 1024, row0, col0, acc, la, lb);
  const int tid = threadIdx.x, lane = tid & 63, wave = tid >> 6;
  const int wm = (wave >> 1) * 64, wn = (wave & 1) * 64, lr = lane & 15, lq = lane >> 4;
  const int which = col0 >> 10;                 // uniform: 0=Q 1=K 2=V
  const int h0 = (col0 & 1023) >> 6;
  const int b = row0 >> 10, t0 = row0 & 1023;
  if (which < 2) {
    const float qs = (which == 0) ? LOG2E_SCALE : 1.f;
    #pragma unroll
    for (int mi = 0; mi < 4; mi++)
      #pragma unroll
      for (int ni = 0; ni < 4; ni++)
        #pragma unroll
        for (int r = 0; r < 4; r++) {
          const int row = wm + mi * 16 + lq * 4 + r;
          const int col = wn + ni * 16 + lr;
          lc[row * 132 + col] = f2bf_s((acc[mi][ni][r] + bqkv[col0 + col]) * qs);
        }
    __syncthreads();
    __hip_bfloat16* O = which == 0 ? Q : K;
    #pragma unroll
    for (int c = 0; c < 8; c++) {
      const int f = tid + 256 * c;              // flat 16B-chunk id
      const int r = f >> 4, cc = f & 15;
      const int col = cc * 8;
      const int head = h0 + (col >> 6), d = col & 63;
      float4 vv = *(const float4*)(lc + r * 132 + col);
      *(float4*)(O + (((size_t)(b * 16 + head)) << 16) + (t0 + r) * 64 + d) = vv;
    }
  } else {
    // transposed epilogue: lc[col][row]
    #pragma unroll
    for (int mi = 0; mi < 4; mi++)
      #pragma unroll
      for (int ni = 0; ni < 4; ni++)
        #pragma unroll
        for (int r = 0; r < 4; r++) {
          const int row = wm + mi * 16 + lq * 4 + r;
          const int col = wn + ni * 16 + lr;
          lc[col * 132 + row] = f2bf_s(acc[mi][ni][r] + bqkv[col0 + col]);
        }
    __syncthreads();
    #pragma unroll
    for (int c = 0; c < 8; c++) {
      const int f = tid + 256 * c;
      const int dl = f >> 4, tc = f & 15;       // local d 0..127, t-chunk
      const int head = h0 + (dl >> 6), d = dl & 63;
      float4 vv = *(const float4*)(lc + dl * 132 + tc * 8);
      *(float4*)(Vt + (((size_t)(b * 16 + head)) << 16) + (size_t)d * 1024 +
                 t0 + tc * 8) = vv;
    }
  }
}

// ---- tail V sums: TV[hb][qt][d] = sum_{t >= (qt+1)*128} Vt[hb][d][t] ----
__global__ __launch_bounds__(256) void k_tailv(const __hip_bfloat16* __restrict__ Vt,
                                               float* __restrict__ TV) {
  __shared__ float ts[8][64];
  const int hb = blockIdx.x, tid = threadIdx.x;
  const __hip_bfloat16* Vh = Vt + ((size_t)hb << 16);
  for (int w = tid; w < 512; w += 256) {
    const int kt = w >> 6, d = w & 63;
    const short* p = (const short*)(Vh + (size_t)d * 1024 + kt * 128);
    float s = 0.f;
    for (int j = 0; j < 128; j += 8) {
      bf16x8 v = *(const bf16x8*)(p + j);
      #pragma unroll
      for (int e = 0; e < 8; e++) s += bf2f(v[e]);
    }
    ts[kt][d] = s;
  }
  __syncthreads();
  for (int w = tid; w < 512; w += 256) {
    const int qt = w >> 6, d = w & 63;
    float s = 0.f;
    for (int kt = qt + 1; kt < 8; kt++) s += ts[kt][d];
    TV[((size_t)hb * 8 + qt) * 64 + d] = s;
  }
}

// ---- fused attention: one block = (64 q-rows, one head); 1024 blocks ----
__global__ __launch_bounds__(256, 4) void k_attn(
    const __hip_bfloat16* __restrict__ Q, const __hip_bfloat16* __restrict__ K,
    const __hip_bfloat16* __restrict__ Vt, const float* __restrict__ TV,
    float* __restrict__ y) {
  __shared__ short lp[64 * 130];   // P-tile (padded)
  __shared__ short lkv[128 * 64];  // K-tile then V^T-tile, swizzled
  const int hb = blockIdx.y;
  const int j = (blockIdx.y & 32) ? (15 - (int)blockIdx.x) : (int)blockIdx.x;
  const int q0 = j * 64;
  const int nkt = (j >> 1) + 1;    // K-tiles (128 wide) to compute
  const int tid = threadIdx.x, lane = tid & 63, wave = tid >> 6;
  const int lr = lane & 15, lq = lane >> 4;
  const int wm = wave * 16;        // wave owns q-rows [q0+wm, q0+wm+16)
  const __hip_bfloat16* Qh = Q + ((size_t)hb << 16);
  const __hip_bfloat16* Kh = K + ((size_t)hb << 16);
  const __hip_bfloat16* Vh = Vt + ((size_t)hb << 16);

  // Q A-frags: direct global loads (rows q0+wm+lr, cols s*32+lq*8)
  bf16x8 qf[2];
  #pragma unroll
  for (int s = 0; s < 2; s++)
    qf[s] = *(const bf16x8*)((const short*)Qh +
                             (size_t)(q0 + wm + lr) * 64 + s * 32 + lq * 8);

  f32x4 oacc[4] = {};
  float mrow[4], lrow[4];
  #pragma unroll
  for (int r = 0; r < 4; r++) { mrow[r] = -1e30f; lrow[r] = 0.f; }

  for (int kt = 0; kt < nkt; kt++) {
    const int k0 = kt * 128;
    __syncthreads();  // prev PV frag reads (lp, lkv) done
    for (int c = tid; c < 1024; c += 256)
      stage16(Kh + (size_t)(k0 + (c >> 3)) * 64 + (((c & 7) ^ ((c >> 3) & 7)) << 3),
              lkv + c * 8);
    __syncthreads();  // K visible
    f32x4 sacc[8] = {};
    #pragma unroll
    for (int s = 0; s < 2; s++) {
      bf16x8 bf[8];
      #pragma unroll
      for (int ni = 0; ni < 8; ni++) {
        const int n = ni * 16 + lr;
        bf[ni] = *(const bf16x8*)(lkv + n * 64 + (((s * 4 + lq) ^ (n & 7)) << 3));
      }
      #pragma unroll
      for (int ni = 0; ni < 8; ni++)
        sacc[ni] = __builtin_amdgcn_mfma_f32_16x16x32_bf16(
            qf[s], bf[ni], sacc[ni], 0, 0, 0);
    }
    __syncthreads();  // K frag reads done; lkv free for V
    // V^T tile DMA (overlaps softmax VALU below)
    for (int c = tid; c < 1024; c += 256)
      stage16(Vh + (size_t)(c >> 4) * 1024 + k0 + (((c & 15) ^ ((c >> 4) & 15)) << 3),
              lkv + c * 8);
    // online softmax, base-2 domain
    const bool last = (kt == nkt - 1);
    #pragma unroll
    for (int r = 0; r < 4; r++) {
      const int grow = q0 + wm + lq * 4 + r;   // global q row
      float tmax = -1e30f;
      #pragma unroll
      for (int ni = 0; ni < 8; ni++) {
        float v = sacc[ni][r];
        if (last && (k0 + ni * 16 + lr) > grow) v = MASK2;
        sacc[ni][r] = v;
        tmax = fmaxf(tmax, v);
      }
      #pragma unroll
      for (int msk = 8; msk; msk >>= 1) tmax = fmaxf(tmax, __shfl_xor(tmax, msk));
      const float mn = fmaxf(mrow[r], tmax);
      const float al = __builtin_amdgcn_exp2f(mrow[r] - mn);
      float rs = 0.f;
      #pragma unroll
      for (int ni = 0; ni < 8; ni++) {
        const float pv = __builtin_amdgcn_exp2f(sacc[ni][r] - mn);
        sacc[ni][r] = pv;
        rs += pv;
      }
      #pragma unroll
      for (int msk = 8; msk; msk >>= 1) rs += __shfl_xor(rs, msk);
      mrow[r] = mn;
      lrow[r] = lrow[r] * al + rs;
      #pragma unroll
      for (int ni = 0; ni < 4; ni++) oacc[ni][r] *= al;
    }
    // P -> lp (padded pitch 130)
    #pragma unroll
    for (int r = 0; r < 4; r++) {
      const int row = wm + lq * 4 + r;
      #pragma unroll
      for (int ni = 0; ni < 8; ni++)
        lp[row * 130 + ni * 16 + lr] = f2bf_s(sacc[ni][r]);
    }
    __syncthreads();  // V staged + P written
    #pragma unroll
    for (int ks = 0; ks < 4; ks++) {
      bf16x8 pa, vb[4];
      pa = *(const bf16x8*)(lp + (wm + lr) * 130 + ks * 32 + lq * 8);
      #pragma unroll
      for (int ni = 0; ni < 4; ni++) {
        const int d = ni * 16 + lr;
        vb[ni] = *(const bf16x8*)(lkv + d * 128 + (((ks * 4 + lq) ^ (d & 15)) << 3));
      }
      #pragma unroll
      for (int ni = 0; ni < 4; ni++)
        oacc[ni] = __builtin_amdgcn_mfma_f32_16x16x32_bf16(
            pa, vb[ni], oacc[ni], 0, 0, 0);
    }
  }

  const int b = hb >> 4, h = hb & 15;
  const float cv = (float)(1024 - nkt * 128);
  const float* tv = TV + ((size_t)hb * 8 + (j >> 1)) * 64;
  #pragma unroll
  for (int r = 0; r < 4; r++) {
    const int t = q0 + wm + lq * 4 + r;
    const float tail = __builtin_amdgcn_exp2f(MASK2 - mrow[r]);
    const float inv = 1.f / (lrow[r] + cv * tail);
    #pragma unroll
    for (int ni = 0; ni < 4; ni++) {
      const int d = ni * 16 + lr;
      y[((size_t)(b * 1024 + t) << 10) + h * 64 + d] =
          (oacc[ni][r] + tail * tv[d]) * inv;
    }
  }
}

// ---- MLP1: h2 @ W1t^T + b1 -> exact gelu -> G bf16 [4096,4096] ----
__global__ __launch_bounds__(256) void k_gemm_mlp1(const __hip_bfloat16* __restrict__ h2,
                                                   const __hip_bfloat16* __restrict__ W1t,
                                                   const float* __restrict__ b1,
                                                   __hip_bfloat16* __restrict__ G) {
  __shared__ alignas(16) short smem[16896];
  short* la = smem;
  short* lb = smem + 8192;
  short* lc = smem;
  const int row0 = blockIdx.x * 128, col0 = blockIdx.y * 128;
  f32x4 acc[4][4] = {};
  gemm_core64<128, 128, 64, 64>(h2, 1024, W1t, 1024, 1024, row0, col0, acc, la, lb);
  const int tid = threadIdx.x, lane = tid & 63, wave = tid >> 6;
  const int wm = (wave >> 1) * 64, wn = (wave & 1) * 64, lr = lane & 15, lq = lane >> 4;
  #pragma unroll
  for (int mi = 0; mi < 4; mi++)
    #pragma unroll
    for (int ni = 0; ni < 4; ni++)
      #pragma unroll
      for (int r = 0; r < 4; r++) {
        const int row = wm + mi * 16 + lq * 4 + r;
        const int col = wn + ni * 16 + lr;
        float v = acc[mi][ni][r] + b1[col0 + col];
        v = 0.5f * v * (1.f + erff(v * 0.70710678118654752f));
        lc[row * 132 + col] = f2bf_s(v);
      }
  __syncthreads();
  #pragma unroll
  for (int c = 0; c < 8; c++) {
    const int f = tid + 256 * c;
    const int r = f >> 4, cc = f & 15;
    float4 vv = *(const float4*)(lc + r * 132 + cc * 8);
    *(float4*)(G + ((size_t)(row0 + r) << 12) + col0 + cc * 8) = vv;
  }
}

// ---- MLP2 split-K=2: out += G @ W2t^T (out pre-initialized with b2 + x2) ----
__global__ __launch_bounds__(256) void k_gemm_mlp2(const __hip_bfloat16* __restrict__ G,
                                                   const __hip_bfloat16* __restrict__ W2t,
                                                   float* __restrict__ out) {
  __shared__ alignas(16) short smem[16384];
  short* la = smem;
  short* lb = smem + 8192;
  const int row0 = blockIdx.x * 128, col0 = blockIdx.y * 128;
  const int kOff = blockIdx.z * 2048;
  f32x4 acc[4][4] = {};
  gemm_core64<128, 128, 64, 64>(G + kOff, 4096, W2t + kOff, 4096, 2048,
                                row0, col0, acc, la, lb);
  const int lane = threadIdx.x & 63, wave = threadIdx.x >> 6;
  const int wm = (wave >> 1) * 64, wn = (wave & 1) * 64, lr = lane & 15, lq = lane >> 4;
  #pragma unroll
  for (int mi = 0; mi < 4; mi++)
    #pragma unroll
    for (int ni = 0; ni < 4; ni++)
      #pragma unroll
      for (int r = 0; r < 4; r++) {
        const int grow = row0 + wm + mi * 16 + lq * 4 + r;
        const int gcol = col0 + wn + ni * 16 + lr;
        atomicAdd(out + (((size_t)grow << 10) + gcol), acc[mi][ni][r]);
      }
}

extern "C" void kernel_launch(void* const* d_in, const int* in_sizes, int n_in,
                              void* d_out, int out_size, void* d_ws, size_t ws_size,
                              hipStream_t stream) {
  const float* x     = (const float*)d_in[0];
  const float* ln1_g = (const float*)d_in[1];
  const float* ln1_b = (const float*)d_in[2];
  const float* ln2_g = (const float*)d_in[3];
  const float* ln2_b = (const float*)d_in[4];
  const float* Wq    = (const float*)d_in[5];
  const float* bq    = (const float*)d_in[6];
  const float* Wk    = (const float*)d_in[7];
  const float* bk    = (const float*)d_in[8];
  const float* Wv    = (const float*)d_in[9];
  const float* bv    = (const float*)d_in[10];
  const float* W1    = (const float*)d_in[11];
  const float* b1    = (const float*)d_in[12];
  const float* W2    = (const float*)d_in[13];
  const float* b2    = (const float*)d_in[14];
  float* out = (float*)d_out;

  char* p = (char*)d_ws;
  auto alloc = [&](size_t bytes) { char* r = p; p += (bytes + 255) & ~(size_t)255; return r; };
  __hip_bfloat16* wqkv = (__hip_bfloat16*)alloc(3072 * 1024 * 2);
  __hip_bfloat16* w1t  = (__hip_bfloat16*)alloc(4096 * 1024 * 2);
  __hip_bfloat16* w2t  = (__hip_bfloat16*)alloc(1024 * 4096 * 2);
  float*          bqkv = (float*)alloc(3072 * 4);
  __hip_bfloat16* h1   = (__hip_bfloat16*)alloc(4096 * 1024 * 2);
  __hip_bfloat16* Qb   = (__hip_bfloat16*)alloc((size_t)64 * 65536 * 2);  // [64][1024][64]
  __hip_bfloat16* Kb   = (__hip_bfloat16*)alloc((size_t)64 * 65536 * 2);
  __hip_bfloat16* Vt   = (__hip_bfloat16*)alloc((size_t)64 * 65536 * 2);  // [64][64][1024]
  float*          TV   = (float*)alloc((size_t)64 * 8 * 64 * 4);
  float*          yb   = (float*)alloc((size_t)4096 * 1024 * 4);
  float*          x2   = (float*)alloc((size_t)4096 * 1024 * 4);
  __hip_bfloat16* h2   = (__hip_bfloat16*)alloc(4096 * 1024 * 2);
  __hip_bfloat16* G    = (__hip_bfloat16*)alloc((size_t)4096 * 4096 * 2);
  (void)ws_size; (void)in_sizes; (void)n_in; (void)out_size;

  const dim3 b256(256), bt(32, 8);
  k_tcvt3<<<dim3(32, 32, 3), bt, 0, stream>>>(Wq, Wk, Wv, wqkv);
  k_tcvt<<<dim3(128, 32), bt, 0, stream>>>(W1, w1t, 1024, 4096, 0, 1024);
  k_tcvt<<<dim3(32, 128), bt, 0, stream>>>(W2, w2t, 4096, 1024, 0, 4096);
  k_pack_bias<<<12, b256, 0, stream>>>(bq, bk, bv, bqkv);

  k_ln<<<4096, b256, 0, stream>>>(x, nullptr, ln1_g, ln1_b, h1, nullptr, nullptr, nullptr);
  k_gemm_qkv<<<dim3(32, 24), b256, 0, stream>>>(h1, wqkv, bqkv, Qb, Kb, Vt);
  k_tailv<<<64, b256, 0, stream>>>(Vt, TV);
  k_attn<<<dim3(16, 64), b256, 0, stream>>>(Qb, Kb, Vt, TV, yb);

  k_ln<<<4096, b256, 0, stream>>>(x, yb, ln2_g, ln2_b, h2, x2, b2, out);
  k_gemm_mlp1<<<dim3(32, 32), b256, 0, stream>>>(h2, w1t, b1, G);
  k_gemm_mlp2<<<dim3(32, 8, 2), b256, 0, stream>>>(G, w2t, out);
}

// Round 10
// 329.014 us; speedup vs baseline: 1.1163x; 1.0312x over previous
//
#include <hip/hip_runtime.h>
#include <hip/hip_bf16.h>
#include <math.h>

// Transformer block (pre-LN attn + MLP), B=4 T=1024 H=1024 K=16 HD=64.
// GEMMs: bf16 MFMA 16x16x32, global_load_lds width=16 staging, BK=64 with
// xor-swizzled LDS chunk placement (0 bank conflicts, verified R8).
// R10: same as R9 (mlp1/mlp2 128x64 tiles -> 2048/1024 blocks) with the
// mlp1 epilogue store loop FIXED: 128x64 tile = 1024 16B chunks -> c<4
// (R9's c<2 left rows 64..127 of each G tile poisoned -> absmax 2.6).
// Attention: fused flash-style, 64-row Q-tiles, exp2-domain softmax (scale
// folded into Q); masked logits FILLED with 1e-9; fully-masked K-tiles
// contribute exp(1e-9-m)*suffixV analytically (TV precomputed).

typedef __attribute__((ext_vector_type(8))) short bf16x8;
typedef __attribute__((ext_vector_type(4))) float f32x4;

#define DEVINL __device__ __forceinline__

#define LOG2E_SCALE 0.18033688f      /* 0.125 * log2(e) */
#define MASK2 1.4426950408889634e-9f /* 1e-9 * log2(e) */

DEVINL void stage16(const __hip_bfloat16* g, short* l) {
  __builtin_amdgcn_global_load_lds(
      (const __attribute__((address_space(1))) unsigned int*)g,
      (__attribute__((address_space(3))) unsigned int*)l, 16, 0, 0);
}

DEVINL float bf2f(short u) {
  unsigned x = ((unsigned)(unsigned short)u) << 16;
  float f; __builtin_memcpy(&f, &x, 4); return f;
}

DEVINL short f2bf_s(float f) {
  __hip_bfloat16 h = __float2bfloat16(f);
  short s; __builtin_memcpy(&s, &h, 2); return s;
}

DEVINL float block_sum(float v, float* sb) {
  #pragma unroll
  for (int o = 32; o; o >>= 1) v += __shfl_down(v, o);
  const int lane = threadIdx.x & 63, w = threadIdx.x >> 6;
  if (lane == 0) sb[w] = v;
  __syncthreads();
  float r = sb[0] + sb[1] + sb[2] + sb[3];
  __syncthreads();
  return r;
}

// ---- GEMM core BK=64: C[M,N] += A[M,Kd] * Bt[N,Kd]^T, 256 threads ----
template<int BM, int BN, int WM, int WN>
DEVINL void gemm_core64(const __hip_bfloat16* __restrict__ A, int lda,
                        const __hip_bfloat16* __restrict__ Bt, int ldb,
                        int Kd, int row0, int col0,
                        f32x4 (&acc)[WM/16][WN/16],
                        short* lds_a, short* lds_b) {
  constexpr int MI = WM / 16, NI = WN / 16, WNC = BN / WN;
  constexpr int CA = BM * 8, CB = BN * 8;  // 16B chunks per tile
  const int tid = threadIdx.x;
  const int lane = tid & 63, wave = tid >> 6;
  const int wm = (wave / WNC) * WM, wn = (wave % WNC) * WN;
  const int lr = lane & 15, lq = lane >> 4;
  for (int k0 = 0; k0 < Kd; k0 += 64) {
    #pragma unroll
    for (int c = tid; c < CA; c += 256) {
      const int r = c >> 3, kc = ((c & 7) ^ (r & 7)) << 3;
      stage16(A + (size_t)(row0 + r) * lda + k0 + kc, lds_a + c * 8);
    }
    #pragma unroll
    for (int c = tid; c < CB; c += 256) {
      const int r = c >> 3, kc = ((c & 7) ^ (r & 7)) << 3;
      stage16(Bt + (size_t)(col0 + r) * ldb + k0 + kc, lds_b + c * 8);
    }
    __syncthreads();
    #pragma unroll
    for (int s = 0; s < 2; s++) {
      bf16x8 af[MI], bfr[NI];
      #pragma unroll
      for (int mi = 0; mi < MI; mi++) {
        const int m = wm + mi * 16 + lr;
        af[mi] = *(const bf16x8*)(lds_a + m * 64 + (((s * 4 + lq) ^ (m & 7)) << 3));
      }
      #pragma unroll
      for (int ni = 0; ni < NI; ni++) {
        const int n = wn + ni * 16 + lr;
        bfr[ni] = *(const bf16x8*)(lds_b + n * 64 + (((s * 4 + lq) ^ (n & 7)) << 3));
      }
      #pragma unroll
      for (int mi = 0; mi < MI; mi++)
        #pragma unroll
        for (int ni = 0; ni < NI; ni++)
          acc[mi][ni] = __builtin_amdgcn_mfma_f32_16x16x32_bf16(
              af[mi], bfr[ni], acc[mi][ni], 0, 0, 0);
    }
    __syncthreads();
  }
}

// ---- transpose + f32->bf16: src[R][C] -> dst[(c+off)][r], dst pitch P ----
__global__ __launch_bounds__(256) void k_tcvt(const float* __restrict__ src,
                                              __hip_bfloat16* __restrict__ dst,
                                              int R, int C, int dstOff, int dstPitch) {
  __shared__ float tile[32][33];
  const int c0 = blockIdx.x * 32, r0 = blockIdx.y * 32;
  const int tx = threadIdx.x, ty = threadIdx.y;  // (32,8)
  #pragma unroll
  for (int i = 0; i < 32; i += 8)
    tile[ty + i][tx] = src[(size_t)(r0 + ty + i) * C + c0 + tx];
  __syncthreads();
  #pragma unroll
  for (int i = 0; i < 32; i += 8)
    dst[(size_t)(c0 + ty + i + dstOff) * dstPitch + r0 + tx] =
        __float2bfloat16(tile[tx][ty + i]);
}

// fused Wq/Wk/Wv transpose (z picks source; all 1024x1024, dst pitch 1024)
__global__ __launch_bounds__(256) void k_tcvt3(const float* __restrict__ Wq,
                                               const float* __restrict__ Wk,
                                               const float* __restrict__ Wv,
                                               __hip_bfloat16* __restrict__ dst) {
  __shared__ float tile[32][33];
  const float* src = blockIdx.z == 0 ? Wq : (blockIdx.z == 1 ? Wk : Wv);
  const int dstOff = blockIdx.z << 10;
  const int c0 = blockIdx.x * 32, r0 = blockIdx.y * 32;
  const int tx = threadIdx.x, ty = threadIdx.y;
  #pragma unroll
  for (int i = 0; i < 32; i += 8)
    tile[ty + i][tx] = src[(size_t)(r0 + ty + i) * 1024 + c0 + tx];
  __syncthreads();
  #pragma unroll
  for (int i = 0; i < 32; i += 8)
    dst[(size_t)(c0 + ty + i + dstOff) * 1024 + r0 + tx] =
        __float2bfloat16(tile[tx][ty + i]);
}

__global__ __launch_bounds__(256) void k_pack_bias(const float* __restrict__ bq,
                                                   const float* __restrict__ bk,
                                                   const float* __restrict__ bv,
                                                   float* __restrict__ o) {
  const int i = blockIdx.x * 256 + threadIdx.x;
  if (i < 3072)
    o[i] = i < 1024 ? bq[i] : (i < 2048 ? bk[i - 1024] : bv[i - 2048]);
}

// ---- LayerNorm (+residual add; optionally init out = x2 + b2) ----
__global__ __launch_bounds__(256) void k_ln(const float* __restrict__ x,
                                            const float* __restrict__ y,
                                            const float* __restrict__ g,
                                            const float* __restrict__ bb,
                                            __hip_bfloat16* __restrict__ o,
                                            float* __restrict__ x2o,
                                            const float* __restrict__ badd,
                                            float* __restrict__ oinit) {
  __shared__ float sb[4];
  const int t = threadIdx.x;
  const size_t base = (size_t)blockIdx.x * 1024 + t * 4;
  const int c = t * 4;
  float4 xv = *(const float4*)(x + base);
  if (y) {
    float4 yv = *(const float4*)(y + base);
    xv.x += yv.x; xv.y += yv.y; xv.z += yv.z; xv.w += yv.w;
    *(float4*)(x2o + base) = xv;
    float4 ov;
    ov.x = xv.x + badd[c + 0]; ov.y = xv.y + badd[c + 1];
    ov.z = xv.z + badd[c + 2]; ov.w = xv.w + badd[c + 3];
    *(float4*)(oinit + base) = ov;
  }
  const float mu = block_sum(xv.x + xv.y + xv.z + xv.w, sb) * (1.f / 1024.f);
  const float dx = xv.x - mu, dy = xv.y - mu, dz = xv.z - mu, dw = xv.w - mu;
  const float var = block_sum(dx * dx + dy * dy + dz * dz + dw * dw, sb) * (1.f / 1024.f);
  const float rs = rsqrtf(var + 1e-5f);
  o[base + 0] = __float2bfloat16(dx * rs * g[c + 0] + bb[c + 0]);
  o[base + 1] = __float2bfloat16(dy * rs * g[c + 1] + bb[c + 1]);
  o[base + 2] = __float2bfloat16(dz * rs * g[c + 2] + bb[c + 2]);
  o[base + 3] = __float2bfloat16(dw * rs * g[c + 3] + bb[c + 3]);
}

// ---- QKV GEMM: h1[4096,1024] @ Wqkv_t[3072,1024]^T -> Q/K [hb][t][d], Vt [hb][d][t]
// Q is PRE-SCALED by 0.125*log2e so attention logits are base-2.
__global__ __launch_bounds__(256) void k_gemm_qkv(
    const __hip_bfloat16* __restrict__ h1, const __hip_bfloat16* __restrict__ Wt,
    const float* __restrict__ bqkv, __hip_bfloat16* __restrict__ Q,
    __hip_bfloat16* __restrict__ K, __hip_bfloat16* __restrict__ Vt) {
  __shared__ alignas(16) short smem[16896];   // la(8192) lb(8192) | lc(16896)
  short* la = smem;
  short* lb = smem + 8192;
  short* lc = smem;
  const int row0 = blockIdx.x * 128, col0 = blockIdx.y * 128;
  f32x4 acc[4][4] = {};
  gemm_core64<128, 128, 64, 64>(h1, 1024, Wt, 1024, 1024, row0, col0, acc, la, lb);
  const int tid = threadIdx.x, lane = tid & 63, wave = tid >> 6;
  const int wm = (wave >> 1) * 64, wn = (wave & 1) * 64, lr = lane & 15, lq = lane >> 4;
  const int which = col0 >> 10;                 // uniform: 0=Q 1=K 2=V
  const int h0 = (col0 & 1023) >> 6;
  const int b = row0 >> 10, t0 = row0 & 1023;
  if (which < 2) {
    const float qs = (which == 0) ? LOG2E_SCALE : 1.f;
    #pragma unroll
    for (int mi = 0; mi < 4; mi++)
      #pragma unroll
      for (int ni = 0; ni < 4; ni++)
        #pragma unroll
        for (int r = 0; r < 4; r++) {
          const int row = wm + mi * 16 + lq * 4 + r;
          const int col = wn + ni * 16 + lr;
          lc[row * 132 + col] = f2bf_s((acc[mi][ni][r] + bqkv[col0 + col]) * qs);
        }
    __syncthreads();
    __hip_bfloat16* O = which == 0 ? Q : K;
    #pragma unroll
    for (int c = 0; c < 8; c++) {
      const int f = tid + 256 * c;              // flat 16B-chunk id
      const int r = f >> 4, cc = f & 15;
      const int col = cc * 8;
      const int head = h0 + (col >> 6), d = col & 63;
      float4 vv = *(const float4*)(lc + r * 132 + col);
      *(float4*)(O + (((size_t)(b * 16 + head)) << 16) + (t0 + r) * 64 + d) = vv;
    }
  } else {
    // transposed epilogue: lc[col][row]
    #pragma unroll
    for (int mi = 0; mi < 4; mi++)
      #pragma unroll
      for (int ni = 0; ni < 4; ni++)
        #pragma unroll
        for (int r = 0; r < 4; r++) {
          const int row = wm + mi * 16 + lq * 4 + r;
          const int col = wn + ni * 16 + lr;
          lc[col * 132 + row] = f2bf_s(acc[mi][ni][r] + bqkv[col0 + col]);
        }
    __syncthreads();
    #pragma unroll
    for (int c = 0; c < 8; c++) {
      const int f = tid + 256 * c;
      const int dl = f >> 4, tc = f & 15;       // local d 0..127, t-chunk
      const int head = h0 + (dl >> 6), d = dl & 63;
      float4 vv = *(const float4*)(lc + dl * 132 + tc * 8);
      *(float4*)(Vt + (((size_t)(b * 16 + head)) << 16) + (size_t)d * 1024 +
                 t0 + tc * 8) = vv;
    }
  }
}

// ---- tail V sums: TV[hb][qt][d] = sum_{t >= (qt+1)*128} Vt[hb][d][t] ----
__global__ __launch_bounds__(256) void k_tailv(const __hip_bfloat16* __restrict__ Vt,
                                               float* __restrict__ TV) {
  __shared__ float ts[8][64];
  const int hb = blockIdx.x, tid = threadIdx.x;
  const __hip_bfloat16* Vh = Vt + ((size_t)hb << 16);
  for (int w = tid; w < 512; w += 256) {
    const int kt = w >> 6, d = w & 63;
    const short* p = (const short*)(Vh + (size_t)d * 1024 + kt * 128);
    float s = 0.f;
    for (int j = 0; j < 128; j += 8) {
      bf16x8 v = *(const bf16x8*)(p + j);
      #pragma unroll
      for (int e = 0; e < 8; e++) s += bf2f(v[e]);
    }
    ts[kt][d] = s;
  }
  __syncthreads();
  for (int w = tid; w < 512; w += 256) {
    const int qt = w >> 6, d = w & 63;
    float s = 0.f;
    for (int kt = qt + 1; kt < 8; kt++) s += ts[kt][d];
    TV[((size_t)hb * 8 + qt) * 64 + d] = s;
  }
}

// ---- fused attention: one block = (64 q-rows, one head); 1024 blocks ----
__global__ __launch_bounds__(256, 4) void k_attn(
    const __hip_bfloat16* __restrict__ Q, const __hip_bfloat16* __restrict__ K,
    const __hip_bfloat16* __restrict__ Vt, const float* __restrict__ TV,
    float* __restrict__ y) {
  __shared__ short lp[64 * 130];   // P-tile (padded)
  __shared__ short lkv[128 * 64];  // K-tile then V^T-tile, swizzled
  const int hb = blockIdx.y;
  const int j = (blockIdx.y & 32) ? (15 - (int)blockIdx.x) : (int)blockIdx.x;
  const int q0 = j * 64;
  const int nkt = (j >> 1) + 1;    // K-tiles (128 wide) to compute
  const int tid = threadIdx.x, lane = tid & 63, wave = tid >> 6;
  const int lr = lane & 15, lq = lane >> 4;
  const int wm = wave * 16;        // wave owns q-rows [q0+wm, q0+wm+16)
  const __hip_bfloat16* Qh = Q + ((size_t)hb << 16);
  const __hip_bfloat16* Kh = K + ((size_t)hb << 16);
  const __hip_bfloat16* Vh = Vt + ((size_t)hb << 16);

  // Q A-frags: direct global loads (rows q0+wm+lr, cols s*32+lq*8)
  bf16x8 qf[2];
  #pragma unroll
  for (int s = 0; s < 2; s++)
    qf[s] = *(const bf16x8*)((const short*)Qh +
                             (size_t)(q0 + wm + lr) * 64 + s * 32 + lq * 8);

  f32x4 oacc[4] = {};
  float mrow[4], lrow[4];
  #pragma unroll
  for (int r = 0; r < 4; r++) { mrow[r] = -1e30f; lrow[r] = 0.f; }

  for (int kt = 0; kt < nkt; kt++) {
    const int k0 = kt * 128;
    __syncthreads();  // prev PV frag reads (lp, lkv) done
    for (int c = tid; c < 1024; c += 256)
      stage16(Kh + (size_t)(k0 + (c >> 3)) * 64 + (((c & 7) ^ ((c >> 3) & 7)) << 3),
              lkv + c * 8);
    __syncthreads();  // K visible
    f32x4 sacc[8] = {};
    #pragma unroll
    for (int s = 0; s < 2; s++) {
      bf16x8 bf[8];
      #pragma unroll
      for (int ni = 0; ni < 8; ni++) {
        const int n = ni * 16 + lr;
        bf[ni] = *(const bf16x8*)(lkv + n * 64 + (((s * 4 + lq) ^ (n & 7)) << 3));
      }
      #pragma unroll
      for (int ni = 0; ni < 8; ni++)
        sacc[ni] = __builtin_amdgcn_mfma_f32_16x16x32_bf16(
            qf[s], bf[ni], sacc[ni], 0, 0, 0);
    }
    __syncthreads();  // K frag reads done; lkv free for V
    // V^T tile DMA (overlaps softmax VALU below)
    for (int c = tid; c < 1024; c += 256)
      stage16(Vh + (size_t)(c >> 4) * 1024 + k0 + (((c & 15) ^ ((c >> 4) & 15)) << 3),
              lkv + c * 8);
    // online softmax, base-2 domain
    const bool last = (kt == nkt - 1);
    #pragma unroll
    for (int r = 0; r < 4; r++) {
      const int grow = q0 + wm + lq * 4 + r;   // global q row
      float tmax = -1e30f;
      #pragma unroll
      for (int ni = 0; ni < 8; ni++) {
        float v = sacc[ni][r];
        if (last && (k0 + ni * 16 + lr) > grow) v = MASK2;
        sacc[ni][r] = v;
        tmax = fmaxf(tmax, v);
      }
      #pragma unroll
      for (int msk = 8; msk; msk >>= 1) tmax = fmaxf(tmax, __shfl_xor(tmax, msk));
      const float mn = fmaxf(mrow[r], tmax);
      const float al = __builtin_amdgcn_exp2f(mrow[r] - mn);
      float rs = 0.f;
      #pragma unroll
      for (int ni = 0; ni < 8; ni++) {
        const float pv = __builtin_amdgcn_exp2f(sacc[ni][r] - mn);
        sacc[ni][r] = pv;
        rs += pv;
      }
      #pragma unroll
      for (int msk = 8; msk; msk >>= 1) rs += __shfl_xor(rs, msk);
      mrow[r] = mn;
      lrow[r] = lrow[r] * al + rs;
      #pragma unroll
      for (int ni = 0; ni < 4; ni++) oacc[ni][r] *= al;
    }
    // P -> lp (padded pitch 130)
    #pragma unroll
    for (int r = 0; r < 4; r++) {
      const int row = wm + lq * 4 + r;
      #pragma unroll
      for (int ni = 0; ni < 8; ni++)
        lp[row * 130 + ni * 16 + lr] = f2bf_s(sacc[ni][r]);
    }
    __syncthreads();  // V staged + P written
    #pragma unroll
    for (int ks = 0; ks < 4; ks++) {
      bf16x8 pa, vb[4];
      pa = *(const bf16x8*)(lp + (wm + lr) * 130 + ks * 32 + lq * 8);
      #pragma unroll
      for (int ni = 0; ni < 4; ni++) {
        const int d = ni * 16 + lr;
        vb[ni] = *(const bf16x8*)(lkv + d * 128 + (((ks * 4 + lq) ^ (d & 15)) << 3));
      }
      #pragma unroll
      for (int ni = 0; ni < 4; ni++)
        oacc[ni] = __builtin_amdgcn_mfma_f32_16x16x32_bf16(
            pa, vb[ni], oacc[ni], 0, 0, 0);
    }
  }

  const int b = hb >> 4, h = hb & 15;
  const float cv = (float)(1024 - nkt * 128);
  const float* tv = TV + ((size_t)hb * 8 + (j >> 1)) * 64;
  #pragma unroll
  for (int r = 0; r < 4; r++) {
    const int t = q0 + wm + lq * 4 + r;
    const float tail = __builtin_amdgcn_exp2f(MASK2 - mrow[r]);
    const float inv = 1.f / (lrow[r] + cv * tail);
    #pragma unroll
    for (int ni = 0; ni < 4; ni++) {
      const int d = ni * 16 + lr;
      y[((size_t)(b * 1024 + t) << 10) + h * 64 + d] =
          (oacc[ni][r] + tail * tv[d]) * inv;
    }
  }
}

// ---- MLP1: h2 @ W1t^T + b1 -> exact gelu -> G bf16 [4096,4096] ----
// 128x64 tile, grid(32,64): 2048 blocks, LDS 24KB staging / lc pitch 72.
__global__ __launch_bounds__(256) void k_gemm_mlp1(const __hip_bfloat16* __restrict__ h2,
                                                   const __hip_bfloat16* __restrict__ W1t,
                                                   const float* __restrict__ b1,
                                                   __hip_bfloat16* __restrict__ G) {
  __shared__ alignas(16) short smem[12288];   // la(8192)+lb(4096) | lc(128*72=9216)
  short* la = smem;
  short* lb = smem + 8192;
  short* lc = smem;
  const int row0 = blockIdx.x * 128, col0 = blockIdx.y * 64;
  f32x4 acc[4][2] = {};
  gemm_core64<128, 64, 64, 32>(h2, 1024, W1t, 1024, 1024, row0, col0, acc, la, lb);
  const int tid = threadIdx.x, lane = tid & 63, wave = tid >> 6;
  const int wm = (wave >> 1) * 64, wn = (wave & 1) * 32, lr = lane & 15, lq = lane >> 4;
  #pragma unroll
  for (int mi = 0; mi < 4; mi++)
    #pragma unroll
    for (int ni = 0; ni < 2; ni++)
      #pragma unroll
      for (int r = 0; r < 4; r++) {
        const int row = wm + mi * 16 + lq * 4 + r;
        const int col = wn + ni * 16 + lr;
        float v = acc[mi][ni][r] + b1[col0 + col];
        v = 0.5f * v * (1.f + erff(v * 0.70710678118654752f));
        lc[row * 72 + col] = f2bf_s(v);
      }
  __syncthreads();
  #pragma unroll
  for (int c = 0; c < 4; c++) {                 // 1024 chunks of 16B (128x64 tile)
    const int f = tid + 256 * c;
    const int r = f >> 3, cc = f & 7;
    float4 vv = *(const float4*)(lc + r * 72 + cc * 8);
    *(float4*)(G + ((size_t)(row0 + r) << 12) + col0 + cc * 8) = vv;
  }
}

// ---- MLP2 split-K=2: out += G @ W2t^T (out pre-initialized with b2 + x2) ----
// 128x64 tile, grid(32,16,2): 1024 blocks, LDS 24KB.
__global__ __launch_bounds__(256) void k_gemm_mlp2(const __hip_bfloat16* __restrict__ G,
                                                   const __hip_bfloat16* __restrict__ W2t,
                                                   float* __restrict__ out) {
  __shared__ alignas(16) short smem[12288];
  short* la = smem;
  short* lb = smem + 8192;
  const int row0 = blockIdx.x * 128, col0 = blockIdx.y * 64;
  const int kOff = blockIdx.z * 2048;
  f32x4 acc[4][2] = {};
  gemm_core64<128, 64, 64, 32>(G + kOff, 4096, W2t + kOff, 4096, 2048,
                               row0, col0, acc, la, lb);
  const int lane = threadIdx.x & 63, wave = threadIdx.x >> 6;
  const int wm = (wave >> 1) * 64, wn = (wave & 1) * 32, lr = lane & 15, lq = lane >> 4;
  #pragma unroll
  for (int mi = 0; mi < 4; mi++)
    #pragma unroll
    for (int ni = 0; ni < 2; ni++)
      #pragma unroll
      for (int r = 0; r < 4; r++) {
        const int grow = row0 + wm + mi * 16 + lq * 4 + r;
        const int gcol = col0 + wn + ni * 16 + lr;
        atomicAdd(out + (((size_t)grow << 10) + gcol), acc[mi][ni][r]);
      }
}

extern "C" void kernel_launch(void* const* d_in, const int* in_sizes, int n_in,
                              void* d_out, int out_size, void* d_ws, size_t ws_size,
                              hipStream_t stream) {
  const float* x     = (const float*)d_in[0];
  const float* ln1_g = (const float*)d_in[1];
  const float* ln1_b = (const float*)d_in[2];
  const float* ln2_g = (const float*)d_in[3];
  const float* ln2_b = (const float*)d_in[4];
  const float* Wq    = (const float*)d_in[5];
  const float* bq    = (const float*)d_in[6];
  const float* Wk    = (const float*)d_in[7];
  const float* bk    = (const float*)d_in[8];
  const float* Wv    = (const float*)d_in[9];
  const float* bv    = (const float*)d_in[10];
  const float* W1    = (const float*)d_in[11];
  const float* b1    = (const float*)d_in[12];
  const float* W2    = (const float*)d_in[13];
  const float* b2    = (const float*)d_in[14];
  float* out = (float*)d_out;

  char* p = (char*)d_ws;
  auto alloc = [&](size_t bytes) { char* r = p; p += (bytes + 255) & ~(size_t)255; return r; };
  __hip_bfloat16* wqkv = (__hip_bfloat16*)alloc(3072 * 1024 * 2);
  __hip_bfloat16* w1t  = (__hip_bfloat16*)alloc(4096 * 1024 * 2);
  __hip_bfloat16* w2t  = (__hip_bfloat16*)alloc(1024 * 4096 * 2);
  float*          bqkv = (float*)alloc(3072 * 4);
  __hip_bfloat16* h1   = (__hip_bfloat16*)alloc(4096 * 1024 * 2);
  __hip_bfloat16* Qb   = (__hip_bfloat16*)alloc((size_t)64 * 65536 * 2);  // [64][1024][64]
  __hip_bfloat16* Kb   = (__hip_bfloat16*)alloc((size_t)64 * 65536 * 2);
  __hip_bfloat16* Vt   = (__hip_bfloat16*)alloc((size_t)64 * 65536 * 2);  // [64][64][1024]
  float*          TV   = (float*)alloc((size_t)64 * 8 * 64 * 4);
  float*          yb   = (float*)alloc((size_t)4096 * 1024 * 4);
  float*          x2   = (float*)alloc((size_t)4096 * 1024 * 4);
  __hip_bfloat16* h2   = (__hip_bfloat16*)alloc(4096 * 1024 * 2);
  __hip_bfloat16* G    = (__hip_bfloat16*)alloc((size_t)4096 * 4096 * 2);
  (void)ws_size; (void)in_sizes; (void)n_in; (void)out_size;

  const dim3 b256(256), bt(32, 8);
  k_tcvt3<<<dim3(32, 32, 3), bt, 0, stream>>>(Wq, Wk, Wv, wqkv);
  k_tcvt<<<dim3(128, 32), bt, 0, stream>>>(W1, w1t, 1024, 4096, 0, 1024);
  k_tcvt<<<dim3(32, 128), bt, 0, stream>>>(W2, w2t, 4096, 1024, 0, 4096);
  k_pack_bias<<<12, b256, 0, stream>>>(bq, bk, bv, bqkv);

  k_ln<<<4096, b256, 0, stream>>>(x, nullptr, ln1_g, ln1_b, h1, nullptr, nullptr, nullptr);
  k_gemm_qkv<<<dim3(32, 24), b256, 0, stream>>>(h1, wqkv, bqkv, Qb, Kb, Vt);
  k_tailv<<<64, b256, 0, stream>>>(Vt, TV);
  k_attn<<<dim3(16, 64), b256, 0, stream>>>(Qb, Kb, Vt, TV, yb);

  k_ln<<<4096, b256, 0, stream>>>(x, yb, ln2_g, ln2_b, h2, x2, b2, out);
  k_gemm_mlp1<<<dim3(32, 64), b256, 0, stream>>>(h2, w1t, b1, G);
  k_gemm_mlp2<<<dim3(32, 16, 2), b256, 0, stream>>>(G, w2t, out);
}